// Round 1
// baseline (1304.878 us; speedup 1.0000x reference)
//
#include <hip/hip_runtime.h>
#include <hip/hip_fp16.h>

#define I_DIM 1152
#define B_DIM 64
#define J_DIM 64
#define D_DIM 32
#define K_DIM 64
#define JD    2048   // J*D
#define ICHUNK 16
#define NCHUNK 72    // I_DIM / ICHUNK

// -----------------------------------------------------------------------------
// K1: u_hat[b][i][jd] (fp16) = sum_k W[i][jd][k] * x[b][i][k]
// lane = jd within a 64-row chunk; W row lives in 64 VGPRs (coalesced float4
// loads, 16B/lane); x rows are wave-uniform -> s_load; inner loop = pure
// v_fmac_f32 (s,v) stream. Stores are lane-contiguous fp16 (128B/instr).
// -----------------------------------------------------------------------------
__global__ __launch_bounds__(256) void k1_uhat(
    const float* __restrict__ x, const float* __restrict__ W,
    __half* __restrict__ uhat) {
  const int i = blockIdx.x;
  const int t = threadIdx.x;
  const int lane = t & 63;
  const int wave = t >> 6;
  #pragma unroll 1
  for (int c = 0; c < 8; ++c) {
    const int jd0 = wave * 512 + c * 64;
    const float* wrow = W + ((size_t)i * JD + jd0 + lane) * K_DIM;
    float wreg[64];
    #pragma unroll
    for (int q = 0; q < 16; ++q) {
      float4 wv = *(const float4*)(wrow + q * 4);
      wreg[q * 4 + 0] = wv.x; wreg[q * 4 + 1] = wv.y;
      wreg[q * 4 + 2] = wv.z; wreg[q * 4 + 3] = wv.w;
    }
    #pragma unroll 2
    for (int b = 0; b < B_DIM; ++b) {
      const float* xr = x + ((size_t)b * I_DIM + i) * K_DIM;  // wave-uniform
      float u = 0.f;
      #pragma unroll
      for (int k = 0; k < K_DIM; ++k) u = fmaf(xr[k], wreg[k], u);
      uhat[((size_t)b * I_DIM + i) * JD + jd0 + lane] = __float2half(u);
    }
  }
}

// -----------------------------------------------------------------------------
// K3: s0 = (1/J) * sum_i u_hat  -> squash -> v0.  Pure streaming sum.
// grid (8, B): thread owns one jd; squash reduction within 32-lane d-groups.
// -----------------------------------------------------------------------------
__global__ __launch_bounds__(256) void k3_s0(
    const __half* __restrict__ uhat, float* __restrict__ v0) {
  const int b = blockIdx.y;
  const int jd = blockIdx.x * 256 + threadIdx.x;
  const __half* p = uhat + (size_t)b * ((size_t)I_DIM * JD) + jd;
  float s = 0.f;
  #pragma unroll 16
  for (int i = 0; i < I_DIM; ++i) s += __half2float(p[(size_t)i * JD]);
  s *= (1.f / 64.f);
  float n2 = s * s;
  #pragma unroll
  for (int w = 1; w < 32; w <<= 1) n2 += __shfl_xor(n2, w);
  const float sc = n2 / (1.f + n2) * rsqrtf(n2 + 1e-9f);
  v0[(size_t)b * JD + jd] = s * sc;
}

// -----------------------------------------------------------------------------
// K4: one routing pass. For each (b,i): a_j = <u_hat[b,i,j,:], v[b,j,:]>,
// c = softmax_j(a), s_partial[j,d] += c_j * u_hat.  One wave per (b, i-chunk).
// lane -> (j = q*16 + lane>>2, d0 = (lane&3)*8), q = 0..3.
// -----------------------------------------------------------------------------
__global__ __launch_bounds__(64) void k4_route(
    const __half* __restrict__ uhat, const float* __restrict__ v,
    float* __restrict__ spart) {
  const int chunk = blockIdx.x;   // 0..NCHUNK-1
  const int b = blockIdx.y;       // 0..63
  const int lane = threadIdx.x;   // 0..63
  const int jq = lane >> 2;       // 0..15
  const int d0 = (lane & 3) * 8;

  float vr[4][8];
  #pragma unroll
  for (int q = 0; q < 4; ++q) {
    const float* vp = v + ((size_t)b * J_DIM + q * 16 + jq) * D_DIM + d0;
    float4 a0 = *(const float4*)vp;
    float4 a1 = *(const float4*)(vp + 4);
    vr[q][0] = a0.x; vr[q][1] = a0.y; vr[q][2] = a0.z; vr[q][3] = a0.w;
    vr[q][4] = a1.x; vr[q][5] = a1.y; vr[q][6] = a1.z; vr[q][7] = a1.w;
  }
  float sacc[4][8];
  #pragma unroll
  for (int q = 0; q < 4; ++q)
    #pragma unroll
    for (int cc = 0; cc < 8; ++cc) sacc[q][cc] = 0.f;

  for (int ii = 0; ii < ICHUNK; ++ii) {
    const int i = chunk * ICHUNK + ii;
    const __half* row = uhat + ((size_t)b * I_DIM + i) * JD;
    float ur[4][8];
    float a[4];
    #pragma unroll
    for (int q = 0; q < 4; ++q) {
      uint4 raw = *(const uint4*)&row[q * 512 + lane * 8];
      const __half* hp = (const __half*)&raw;
      float p = 0.f;
      #pragma unroll
      for (int cc = 0; cc < 8; ++cc) {
        ur[q][cc] = __half2float(hp[cc]);
        p = fmaf(ur[q][cc], vr[q][cc], p);
      }
      p += __shfl_xor(p, 1);
      p += __shfl_xor(p, 2);
      a[q] = p;  // a[b, j=q*16+jq], replicated over the quad
    }
    float m = fmaxf(fmaxf(a[0], a[1]), fmaxf(a[2], a[3]));
    #pragma unroll
    for (int w = 4; w < 64; w <<= 1) m = fmaxf(m, __shfl_xor(m, w));
    float e[4]; float es = 0.f;
    #pragma unroll
    for (int q = 0; q < 4; ++q) { e[q] = __expf(a[q] - m); es += e[q]; }
    #pragma unroll
    for (int w = 4; w < 64; w <<= 1) es += __shfl_xor(es, w);
    const float inv = 4.f / es;  // each j counted 4x in the wave sum
    #pragma unroll
    for (int q = 0; q < 4; ++q) {
      const float cj = e[q] * inv;
      #pragma unroll
      for (int cc = 0; cc < 8; ++cc)
        sacc[q][cc] = fmaf(cj, ur[q][cc], sacc[q][cc]);
    }
  }
  float* sp = spart + ((size_t)(b * NCHUNK + chunk)) * JD;
  #pragma unroll
  for (int q = 0; q < 4; ++q) {
    float* o = sp + (q * 16 + jq) * D_DIM + d0;
    *(float4*)o       = make_float4(sacc[q][0], sacc[q][1], sacc[q][2], sacc[q][3]);
    *(float4*)(o + 4) = make_float4(sacc[q][4], sacc[q][5], sacc[q][6], sacc[q][7]);
  }
}

// -----------------------------------------------------------------------------
// K5: reduce s-partials over chunks -> squash -> vout.
// If vsum != null: also write vout + vprev (prepares b2 = u_hat . (v0+v1)).
// -----------------------------------------------------------------------------
__global__ __launch_bounds__(256) void k5_reduce(
    const float* __restrict__ spart, const float* __restrict__ vprev,
    float* __restrict__ vout, float* __restrict__ vsum) {
  const int b = blockIdx.y;
  const int jd = blockIdx.x * 256 + threadIdx.x;
  const float* p = spart + (size_t)b * NCHUNK * JD + jd;
  float s = 0.f;
  #pragma unroll 8
  for (int ch = 0; ch < NCHUNK; ++ch) s += p[(size_t)ch * JD];
  float n2 = s * s;
  #pragma unroll
  for (int w = 1; w < 32; w <<= 1) n2 += __shfl_xor(n2, w);
  const float sc = n2 / (1.f + n2) * rsqrtf(n2 + 1e-9f);
  const float vv = s * sc;
  vout[(size_t)b * JD + jd] = vv;
  if (vsum) vsum[(size_t)b * JD + jd] = vv + vprev[(size_t)b * JD + jd];
}

extern "C" void kernel_launch(void* const* d_in, const int* in_sizes, int n_in,
                              void* d_out, int out_size, void* d_ws, size_t ws_size,
                              hipStream_t stream) {
  const float* x = (const float*)d_in[0];   // (B, I, 1, K, 1) f32
  const float* W = (const float*)d_in[1];   // (1, I, J, D, K) f32
  float* out = (float*)d_out;               // (B, J, 1, D, 1) f32

  char* ws = (char*)d_ws;
  __half* uhat = (__half*)ws;                                   // 302 MB
  size_t off = (size_t)B_DIM * I_DIM * JD * sizeof(__half);
  float* spart = (float*)(ws + off);
  off += (size_t)B_DIM * NCHUNK * JD * sizeof(float);           // 36 MB
  float* v0 = (float*)(ws + off);   off += (size_t)B_DIM * JD * sizeof(float);
  float* v1 = (float*)(ws + off);   off += (size_t)B_DIM * JD * sizeof(float);
  float* vsum = (float*)(ws + off);

  // u_hat
  k1_uhat<<<I_DIM, 256, 0, stream>>>(x, W, uhat);
  // it 0: c uniform 1/J -> s0 -> v0
  k3_s0<<<dim3(8, B_DIM), 256, 0, stream>>>(uhat, v0);
  // it 1: b1 = u.v0 -> softmax -> s1 -> v1 (and vsum = v0+v1)
  k4_route<<<dim3(NCHUNK, B_DIM), 64, 0, stream>>>(uhat, v0, spart);
  k5_reduce<<<dim3(8, B_DIM), 256, 0, stream>>>(spart, v0, v1, vsum);
  // it 2: b2 = u.(v0+v1) -> softmax -> s2 -> v2 = output
  k4_route<<<dim3(NCHUNK, B_DIM), 64, 0, stream>>>(uhat, vsum, spart);
  k5_reduce<<<dim3(8, B_DIM), 256, 0, stream>>>(spart, nullptr, out, nullptr);
}

// Round 2
// 596.926 us; speedup vs baseline: 2.1860x; 2.1860x over previous
//
#include <hip/hip_runtime.h>
#include <hip/hip_fp16.h>

#define I_DIM 1152
#define B_DIM 64
#define J_DIM 64
#define D_DIM 32
#define K_DIM 64
#define JD    2048   // J*D
#define ICHUNK 16
#define NCHUNK 72    // I_DIM / ICHUNK
#define G_I   18     // i's per k1 block
#define NGRP  (I_DIM / G_I)   // 64 i-groups

typedef _Float16 half8 __attribute__((ext_vector_type(8)));
typedef float f32x4 __attribute__((ext_vector_type(4)));

// Load 8 consecutive f32 and split each into fp16 hi + fp16 lo (residual).
// u = xh*wh + xh*wl + xl*wh reproduces the f32 product to ~2^-21 rel.
__device__ inline void load_split(const float* __restrict__ p, half8& hi, half8& lo) {
  float4 f0 = *(const float4*)p;
  float4 f1 = *(const float4*)(p + 4);
  float f[8] = {f0.x, f0.y, f0.z, f0.w, f1.x, f1.y, f1.z, f1.w};
  #pragma unroll
  for (int e = 0; e < 8; ++e) {
    _Float16 h = (_Float16)f[e];
    hi[e] = h;
    lo[e] = (_Float16)(f[e] - (float)h);
  }
}

// -----------------------------------------------------------------------------
// K1 (MFMA): u_hat[b][i][jd] fp16 = sum_k W[i][jd][k] * x[b][i][k]
// Per i this is a 64(b) x 2048(jd) x 64(k) GEMM with both operands k-contiguous.
// Block = 4 waves; wave w owns 16 jd cols (n-tile), all 4 m-tiles (b=0..63).
// mfma_f32_16x16x32_f16: A lane l -> row=l&15, k=(l>>4)*8+e ; B lane l ->
// col=l&15, k=(l>>4)*8+e ; C/D -> col=lane&15, row=(lane>>4)*4+reg.
// s0 = sum_i u_hat accumulates for free in f32 regs -> spart0 partials
// (kills the separate 302MB-read reduction kernel).
// -----------------------------------------------------------------------------
__global__ __launch_bounds__(256) void k1_uhat(
    const float* __restrict__ x, const float* __restrict__ W,
    __half* __restrict__ uhat, float* __restrict__ spart0) {
  const int g   = blockIdx.x;              // i-group, fastest -> XCD keeps x slice
  const int jd0 = blockIdx.y * 64;         // 32 jd-chunks
  const int lane = threadIdx.x & 63;
  const int wave = threadIdx.x >> 6;
  const int col = jd0 + wave * 16 + (lane & 15);   // this lane's jd (B/C col)
  const int kof = (lane >> 4) * 8;                 // k sub-offset

  f32x4 s0a[4];
  #pragma unroll
  for (int m = 0; m < 4; ++m) s0a[m] = (f32x4)0.f;

  #pragma unroll 1
  for (int ii = 0; ii < G_I; ++ii) {
    const int i = g * G_I + ii;
    // B frags: W row `col`, k = kof(+32)
    const float* wrow = W + ((size_t)i * JD + col) * K_DIM + kof;
    half8 bh0, bl0, bh1, bl1;
    load_split(wrow,      bh0, bl0);
    load_split(wrow + 32, bh1, bl1);

    f32x4 c[4];
    #pragma unroll
    for (int m = 0; m < 4; ++m) {
      const float* xrow = x + ((size_t)(m * 16 + (lane & 15)) * I_DIM + i) * K_DIM + kof;
      half8 ah0, al0, ah1, al1;
      load_split(xrow,      ah0, al0);
      load_split(xrow + 32, ah1, al1);
      f32x4 acc = {0.f, 0.f, 0.f, 0.f};
      acc = __builtin_amdgcn_mfma_f32_16x16x32_f16(ah0, bh0, acc, 0, 0, 0);
      acc = __builtin_amdgcn_mfma_f32_16x16x32_f16(ah1, bh1, acc, 0, 0, 0);
      acc = __builtin_amdgcn_mfma_f32_16x16x32_f16(ah0, bl0, acc, 0, 0, 0);
      acc = __builtin_amdgcn_mfma_f32_16x16x32_f16(ah1, bl1, acc, 0, 0, 0);
      acc = __builtin_amdgcn_mfma_f32_16x16x32_f16(al0, bh0, acc, 0, 0, 0);
      acc = __builtin_amdgcn_mfma_f32_16x16x32_f16(al1, bh1, acc, 0, 0, 0);
      c[m] = acc;
      s0a[m] += acc;
    }
    // store u_hat fp16: row b = m*16 + (lane>>4)*4 + r, col = `col`
    #pragma unroll
    for (int m = 0; m < 4; ++m) {
      const int brow = m * 16 + ((lane >> 4) << 2);
      #pragma unroll
      for (int r = 0; r < 4; ++r)
        uhat[((size_t)(brow + r) * I_DIM + i) * JD + col] = __float2half(c[m][r]);
    }
  }
  // write s0 partials (sum over this block's 18 i's)
  #pragma unroll
  for (int m = 0; m < 4; ++m) {
    const int brow = m * 16 + ((lane >> 4) << 2);
    #pragma unroll
    for (int r = 0; r < 4; ++r)
      spart0[((size_t)g * B_DIM + brow + r) * JD + col] = s0a[m][r];
  }
}

// -----------------------------------------------------------------------------
// K3b: reduce s0 partials over 64 i-groups, *1/J, squash -> v0.
// -----------------------------------------------------------------------------
__global__ __launch_bounds__(256) void k3b_s0(
    const float* __restrict__ spart0, float* __restrict__ v0) {
  const int b = blockIdx.y;
  const int jd = blockIdx.x * 256 + threadIdx.x;
  const float* p = spart0 + (size_t)b * JD + jd;
  float s = 0.f;
  #pragma unroll 8
  for (int gg = 0; gg < NGRP; ++gg) s += p[(size_t)gg * B_DIM * JD];
  s *= (1.f / 64.f);
  float n2 = s * s;
  #pragma unroll
  for (int w = 1; w < 32; w <<= 1) n2 += __shfl_xor(n2, w);
  const float sc = n2 / (1.f + n2) * rsqrtf(n2 + 1e-9f);
  v0[(size_t)b * JD + jd] = s * sc;
}

// -----------------------------------------------------------------------------
// K4: one routing pass. For each (b,i): a_j = <u_hat[b,i,j,:], v[b,j,:]>,
// c = softmax_j(a), s_partial[j,d] += c_j * u_hat.  One wave per (b, i-chunk).
// lane -> (j = q*16 + lane>>2, d0 = (lane&3)*8), q = 0..3.
// -----------------------------------------------------------------------------
__global__ __launch_bounds__(64) void k4_route(
    const __half* __restrict__ uhat, const float* __restrict__ v,
    float* __restrict__ spart) {
  const int chunk = blockIdx.x;   // 0..NCHUNK-1
  const int b = blockIdx.y;       // 0..63
  const int lane = threadIdx.x;   // 0..63
  const int jq = lane >> 2;       // 0..15
  const int d0 = (lane & 3) * 8;

  float vr[4][8];
  #pragma unroll
  for (int q = 0; q < 4; ++q) {
    const float* vp = v + ((size_t)b * J_DIM + q * 16 + jq) * D_DIM + d0;
    float4 a0 = *(const float4*)vp;
    float4 a1 = *(const float4*)(vp + 4);
    vr[q][0] = a0.x; vr[q][1] = a0.y; vr[q][2] = a0.z; vr[q][3] = a0.w;
    vr[q][4] = a1.x; vr[q][5] = a1.y; vr[q][6] = a1.z; vr[q][7] = a1.w;
  }
  float sacc[4][8];
  #pragma unroll
  for (int q = 0; q < 4; ++q)
    #pragma unroll
    for (int cc = 0; cc < 8; ++cc) sacc[q][cc] = 0.f;

  for (int ii = 0; ii < ICHUNK; ++ii) {
    const int i = chunk * ICHUNK + ii;
    const __half* row = uhat + ((size_t)b * I_DIM + i) * JD;
    float ur[4][8];
    float a[4];
    #pragma unroll
    for (int q = 0; q < 4; ++q) {
      uint4 raw = *(const uint4*)&row[q * 512 + lane * 8];
      const __half* hp = (const __half*)&raw;
      float p = 0.f;
      #pragma unroll
      for (int cc = 0; cc < 8; ++cc) {
        ur[q][cc] = __half2float(hp[cc]);
        p = fmaf(ur[q][cc], vr[q][cc], p);
      }
      p += __shfl_xor(p, 1);
      p += __shfl_xor(p, 2);
      a[q] = p;  // a[b, j=q*16+jq], replicated over the quad
    }
    float m = fmaxf(fmaxf(a[0], a[1]), fmaxf(a[2], a[3]));
    #pragma unroll
    for (int w = 4; w < 64; w <<= 1) m = fmaxf(m, __shfl_xor(m, w));
    float e[4]; float es = 0.f;
    #pragma unroll
    for (int q = 0; q < 4; ++q) { e[q] = __expf(a[q] - m); es += e[q]; }
    #pragma unroll
    for (int w = 4; w < 64; w <<= 1) es += __shfl_xor(es, w);
    const float inv = 4.f / es;  // each j counted 4x in the wave sum
    #pragma unroll
    for (int q = 0; q < 4; ++q) {
      const float cj = e[q] * inv;
      #pragma unroll
      for (int cc = 0; cc < 8; ++cc)
        sacc[q][cc] = fmaf(cj, ur[q][cc], sacc[q][cc]);
    }
  }
  float* sp = spart + ((size_t)(b * NCHUNK + chunk)) * JD;
  #pragma unroll
  for (int q = 0; q < 4; ++q) {
    float* o = sp + (q * 16 + jq) * D_DIM + d0;
    *(float4*)o       = make_float4(sacc[q][0], sacc[q][1], sacc[q][2], sacc[q][3]);
    *(float4*)(o + 4) = make_float4(sacc[q][4], sacc[q][5], sacc[q][6], sacc[q][7]);
  }
}

// -----------------------------------------------------------------------------
// K5: reduce s-partials over chunks -> squash -> vout.
// If vsum != null: also write vout + vprev (prepares b2 = u_hat . (v0+v1)).
// -----------------------------------------------------------------------------
__global__ __launch_bounds__(256) void k5_reduce(
    const float* __restrict__ spart, const float* __restrict__ vprev,
    float* __restrict__ vout, float* __restrict__ vsum) {
  const int b = blockIdx.y;
  const int jd = blockIdx.x * 256 + threadIdx.x;
  const float* p = spart + (size_t)b * NCHUNK * JD + jd;
  float s = 0.f;
  #pragma unroll 8
  for (int ch = 0; ch < NCHUNK; ++ch) s += p[(size_t)ch * JD];
  float n2 = s * s;
  #pragma unroll
  for (int w = 1; w < 32; w <<= 1) n2 += __shfl_xor(n2, w);
  const float sc = n2 / (1.f + n2) * rsqrtf(n2 + 1e-9f);
  const float vv = s * sc;
  vout[(size_t)b * JD + jd] = vv;
  if (vsum) vsum[(size_t)b * JD + jd] = vv + vprev[(size_t)b * JD + jd];
}

extern "C" void kernel_launch(void* const* d_in, const int* in_sizes, int n_in,
                              void* d_out, int out_size, void* d_ws, size_t ws_size,
                              hipStream_t stream) {
  const float* x = (const float*)d_in[0];   // (B, I, 1, K, 1) f32
  const float* W = (const float*)d_in[1];   // (1, I, J, D, K) f32
  float* out = (float*)d_out;               // (B, J, 1, D, 1) f32

  char* ws = (char*)d_ws;
  __half* uhat = (__half*)ws;                                   // 302 MB
  size_t off = (size_t)B_DIM * I_DIM * JD * sizeof(__half);
  float* spart = (float*)(ws + off);                            // 37.75 MB
  off += (size_t)B_DIM * NCHUNK * JD * sizeof(float);           // (spart0 aliases
  float* v0 = (float*)(ws + off);   off += (size_t)B_DIM * JD * sizeof(float);
  float* v1 = (float*)(ws + off);   off += (size_t)B_DIM * JD * sizeof(float);
  float* vsum = (float*)(ws + off);

  // u_hat via split-fp16 MFMA; s0 partials accumulated for free
  k1_uhat<<<dim3(NGRP, 32), 256, 0, stream>>>(x, W, uhat, spart);
  // it 0: finish s0 reduction -> v0
  k3b_s0<<<dim3(8, B_DIM), 256, 0, stream>>>(spart, v0);
  // it 1: b1 = u.v0 -> softmax -> s1 -> v1 (and vsum = v0+v1)
  k4_route<<<dim3(NCHUNK, B_DIM), 64, 0, stream>>>(uhat, v0, spart);
  k5_reduce<<<dim3(8, B_DIM), 256, 0, stream>>>(spart, v0, v1, vsum);
  // it 2: b2 = u.(v0+v1) -> softmax -> s2 -> v2 = output
  k4_route<<<dim3(NCHUNK, B_DIM), 64, 0, stream>>>(uhat, vsum, spart);
  k5_reduce<<<dim3(8, B_DIM), 256, 0, stream>>>(spart, nullptr, out, nullptr);
}